// Round 6
// baseline (321.532 us; speedup 1.0000x reference)
//
#include <hip/hip_runtime.h>
#include <math.h>

#define POS_W 1.0f
#define ANG_W 1.0f
#define WID_W 1.0f

__device__ __forceinline__ float smooth_l1(float x) {
    float a = fabsf(x);
    return a < 1.0f ? 0.5f * x * x : a - 0.5f;
}

// ---------------------------------------------------------------------------
// Kernel A: per-block (256 counts) sums
// ---------------------------------------------------------------------------
__global__ void k_block_sums(const int* __restrict__ counts, int stride, int n,
                             int* __restrict__ blockSums) {
    int i = blockIdx.x * 256 + threadIdx.x;
    int c = (i < n) ? counts[(long long)i * stride] : 0;
    for (int off = 32; off > 0; off >>= 1) c += __shfl_down(c, off, 64);
    __shared__ int sdata[4];
    int lane = threadIdx.x & 63, wave = threadIdx.x >> 6;
    if (lane == 0) sdata[wave] = c;
    __syncthreads();
    if (threadIdx.x == 0)
        blockSums[blockIdx.x] = sdata[0] + sdata[1] + sdata[2] + sdata[3];
}

// ---------------------------------------------------------------------------
// Kernel B: single-block exclusive scan of blockSums[nb] -> blockOffs[nb]
// ---------------------------------------------------------------------------
__global__ void k_scan_blocks(const int* __restrict__ blockSums, int nb,
                              int* __restrict__ blockOffs) {
    int t = threadIdx.x;
    int per = (nb + 255) / 256;
    int start = t * per;
    int end = min(start + per, nb);
    int sum = 0;
    for (int j = start; j < end; ++j) sum += blockSums[j];
    __shared__ int s[256];
    s[t] = sum;
    __syncthreads();
    for (int d = 1; d < 256; d <<= 1) {
        int v = (t >= d) ? s[t - d] : 0;
        __syncthreads();
        s[t] += v;
        __syncthreads();
    }
    int run = s[t] - sum;
    for (int j = start; j < end; ++j) {
        blockOffs[j] = run;
        run += blockSums[j];
    }
}

// ---------------------------------------------------------------------------
// Kernel C: wave-private barrier-free streaming.
// Each wave owns 64 preds and their contiguous target window; it streams the
// window through a PRIVATE LDS double buffer (2 x 256 rows x 24B = 12 KB).
// Hot loop has NO __syncthreads: prefetch batch for chunk k+1 stays in
// flight (vmcnt) while chunk k is computed from LDS; only a wave-local
// s_waitcnt lgkmcnt(0) orders ds_write -> ds_read. Waves free-run, so
// memory-queue arrivals are desynchronized across the CU.
// ---------------------------------------------------------------------------
__global__ __launch_bounds__(256) void k_loss(
    const float* __restrict__ pred, const float* __restrict__ tgt,
    const int* __restrict__ counts, int stride, int n,
    const int* __restrict__ blockOffs, float* __restrict__ partials) {
    __shared__ float2 buf[4][2][768];  // 48 KB: per-wave double buffer
    __shared__ int wsum[4];

    int t = threadIdx.x;
    int lane = t & 63, wave = t >> 6;
    int i = blockIdx.x * 256 + t;
    int c = (i < n) ? counts[(long long)i * stride] : 0;

    // wave-level inclusive scan of counts
    int incl = c;
#pragma unroll
    for (int d = 1; d < 64; d <<= 1) {
        int v = __shfl_up(incl, d, 64);
        if (lane >= d) incl += v;
    }
    if (lane == 63) wsum[wave] = incl;
    __syncthreads();  // the ONLY block-wide barrier
    int w0 = wsum[0], w1 = wsum[1], w2 = wsum[2];
    int waveOff = (wave > 0 ? w0 : 0) + (wave > 1 ? w1 : 0) + (wave > 2 ? w2 : 0);
    int offW = incl - c;        // exclusive prefix within the wave
    int totalW = wsum[wave];    // rows this wave consumes
    const float2* win = (const float2*)tgt +
                        (long long)(blockOffs[blockIdx.x] + waveOff) * 3;

    bool active = (i < n) && (c > 0);
    float p0 = 0, p1 = 0, p2 = 0, p3 = 0, p4 = 0;
    if (i < n) {
        const float2* p2p = (const float2*)(pred + (long long)i * 6);
        float2 a = p2p[0], b = p2p[1], w = p2p[2];
        p0 = a.x; p1 = a.y; p2 = b.x; p3 = b.y; p4 = w.x;
    }

    float best = INFINITY;
    float b0 = 0, b1 = 0, b2 = 0, b3 = 0, b4 = 0;

    if (totalW > 0) {
        int totalF2 = totalW * 3;           // <= 3072
        float2 r[12];
        float2(*mybuf)[768] = buf[wave];
        // prologue: issue chunk 0 (12 coalesced float2 per lane, clamped)
#pragma unroll
        for (int j = 0; j < 12; ++j)
            r[j] = win[min(lane + 64 * j, totalF2 - 1)];

        int nch = (totalW + 255) >> 8;
        for (int ck = 0; ck < nch; ++ck) {
            float2* bb = mybuf[ck & 1];
            // regs -> LDS (compiler inserts vmcnt waits for r[])
#pragma unroll
            for (int j = 0; j < 12; ++j) bb[lane + 64 * j] = r[j];
            // issue next chunk's loads; they stay in flight during compute
            if (ck + 1 < nch) {
                int kb = (ck + 1) * 768 + lane;
#pragma unroll
                for (int j = 0; j < 12; ++j)
                    r[j] = win[min(kb + 64 * j, totalF2 - 1)];
            }
            // wave-local: ensure our ds_writes landed before cross-lane reads
            asm volatile("s_waitcnt lgkmcnt(0)" ::: "memory");
            __builtin_amdgcn_wave_barrier();
            int base = ck << 8;
            int lo = max(offW, base), hi = min(offW + c, base + 256);
            for (int rr = lo; rr < hi; ++rr) {
                int l3 = (rr - base) * 3;
                float2 ga = bb[l3], gb = bb[l3 + 1], gw = bb[l3 + 2];
                float d0 = p0 - ga.x, d1 = p1 - ga.y;
                float d2 = p2 - gb.x, d3 = p3 - gb.y;
                float d4 = p4 - gw.x;
                float dist = POS_W * (d0 * d0 + d1 * d1) +
                             ANG_W * (d2 * d2 + d3 * d3) + WID_W * d4 * d4;
                if (dist < best) {  // strict <: first occurrence, matches ref
                    best = dist;
                    b0 = ga.x; b1 = ga.y; b2 = gb.x; b3 = gb.y; b4 = gw.x;
                }
            }
            __builtin_amdgcn_wave_barrier();  // keep later writes after reads
        }
    }

    float loss = 0.0f;
    if (active) {
        loss = POS_W * (smooth_l1(p0 - b0) + smooth_l1(p1 - b1)) +
               ANG_W * (fabsf(p2 - b2) + fabsf(p3 - b3)) +
               WID_W * smooth_l1(p4 - b4);
    }
    for (int o = 32; o > 0; o >>= 1) loss += __shfl_down(loss, o, 64);
    if (lane == 0) partials[blockIdx.x * 4 + wave] = loss;
}

// ---------------------------------------------------------------------------
// Kernel D: single-block reduction of per-wave partials -> out[0]
// ---------------------------------------------------------------------------
__global__ void k_reduce(const float* __restrict__ partials, int np,
                         float invN, float* __restrict__ out) {
    int t = threadIdx.x;
    float s = 0.0f;
    for (int j = t; j < np; j += 256) s += partials[j];
    for (int o = 32; o > 0; o >>= 1) s += __shfl_down(s, o, 64);
    __shared__ float fs[4];
    int lane = t & 63, wave = t >> 6;
    if (lane == 0) fs[wave] = s;
    __syncthreads();
    if (t == 0) out[0] = (fs[0] + fs[1] + fs[2] + fs[3]) * invN;
}

// ---------------------------------------------------------------------------
extern "C" void kernel_launch(void* const* d_in, const int* in_sizes, int n_in,
                              void* d_out, int out_size, void* d_ws,
                              size_t ws_size, hipStream_t stream) {
    const float* pred = (const float*)d_in[0];
    const float* tgt = (const float*)d_in[1];
    const int* counts = (const int*)d_in[2];
    int n = in_sizes[0] / 6;
    int stride = (in_sizes[2] == n) ? 1 : 2;  // int64 counts -> read low words
    int nb = (n + 255) / 256;

    int* blockSums = (int*)d_ws;
    int* blockOffs = blockSums + nb;
    float* partials = (float*)(blockOffs + nb);
    float* out = (float*)d_out;

    k_block_sums<<<nb, 256, 0, stream>>>(counts, stride, n, blockSums);
    k_scan_blocks<<<1, 256, 0, stream>>>(blockSums, nb, blockOffs);
    k_loss<<<nb, 256, 0, stream>>>(pred, tgt, counts, stride, n, blockOffs,
                                   partials);
    k_reduce<<<1, 256, 0, stream>>>(partials, 4 * nb, 1.0f / n, out);
}

// Round 7
// 315.868 us; speedup vs baseline: 1.0179x; 1.0179x over previous
//
#include <hip/hip_runtime.h>
#include <math.h>

#define POS_W 1.0f
#define ANG_W 1.0f
#define WID_W 1.0f
#define PW 512   // preds per persistent wave
#define NT 8     // tiles of 64 preds per wave
#define CH 256   // rows per LDS chunk (6 KB)

__device__ __forceinline__ float smooth_l1(float x) {
    float a = fabsf(x);
    return a < 1.0f ? 0.5f * x * x : a - 0.5f;
}

// ---------------------------------------------------------------------------
// Kernel A: per-wave-span (512 counts) sums
// ---------------------------------------------------------------------------
__global__ void k_span_sums(const int* __restrict__ counts, int stride, int n,
                            int* __restrict__ spanSums) {
    int t = threadIdx.x;
    long long i0 = (long long)blockIdx.x * PW + t;
    long long i1 = i0 + 256;
    int c = (i0 < n ? counts[i0 * stride] : 0) +
            (i1 < n ? counts[i1 * stride] : 0);
    for (int off = 32; off > 0; off >>= 1) c += __shfl_down(c, off, 64);
    __shared__ int sdata[4];
    int lane = t & 63, wave = t >> 6;
    if (lane == 0) sdata[wave] = c;
    __syncthreads();
    if (t == 0)
        spanSums[blockIdx.x] = sdata[0] + sdata[1] + sdata[2] + sdata[3];
}

// ---------------------------------------------------------------------------
// Kernel B: single-block exclusive scan of spanSums[nw] -> waveBase[nw+1]
// ---------------------------------------------------------------------------
__global__ void k_scan_spans(const int* __restrict__ spanSums, int nw,
                             int* __restrict__ waveBase) {
    int t = threadIdx.x;
    int per = (nw + 255) / 256;
    int start = t * per;
    int end = min(start + per, nw);
    int sum = 0;
    for (int j = start; j < end; ++j) sum += spanSums[j];
    __shared__ int s[256];
    s[t] = sum;
    __syncthreads();
    for (int d = 1; d < 256; d <<= 1) {
        int v = (t >= d) ? s[t - d] : 0;
        __syncthreads();
        s[t] += v;
        __syncthreads();
    }
    int run = s[t] - sum;
    for (int j = start; j < end; ++j) {
        waveBase[j] = run;
        run += spanSums[j];
    }
    if (end == nw) waveBase[nw] = run;  // total
}

// ---------------------------------------------------------------------------
// Kernel C: persistent waves. Wave w owns preds [w*512, w*512+512) and their
// contiguous GT window [waveBase[w], waveBase[w+1]) — ONE long stream per
// wave through a private 2x6KB LDS ring, no block barriers in the hot loop.
// Tiles of 64 preds are finalized on the fly as the stream crosses them.
// ---------------------------------------------------------------------------
__global__ __launch_bounds__(256) void k_loss(
    const float* __restrict__ pred, const float* __restrict__ tgt,
    const int* __restrict__ counts, int stride, long long n,
    const int* __restrict__ waveBase, int nw, float* __restrict__ partials) {
    __shared__ float2 ring[4][2][CH * 3];  // 48 KB: per-wave double buffer

    int t = threadIdx.x;
    int lane = t & 63, wv = t >> 6;
    int w = blockIdx.x * 4 + wv;
    if (w >= nw) return;

    long long predStart = (long long)w * PW;
    int rowStart = waveBase[w];
    int totalW = waveBase[w + 1] - rowStart;
    int totalF2 = totalW * 3;
    const float2* win = (const float2*)tgt + (long long)rowStart * 3;

    // per-tile state (tile window is wave-uniform; segment is per-lane)
    int tIdx = -1, tEnd = 0;
    int c = 0, cur = 0, segHi = 0;
    float p0 = 0, p1 = 0, p2 = 0, p3 = 0, p4 = 0;
    float best = INFINITY, b0 = 0, b1 = 0, b2 = 0, b3 = 0, b4 = 0;
    float lossAcc = 0.0f;

    auto finalize = [&]() {
        if (tIdx >= 0) {
            long long ip = predStart + (long long)tIdx * 64 + lane;
            if (ip < n && c > 0)
                lossAcc += POS_W * (smooth_l1(p0 - b0) + smooth_l1(p1 - b1)) +
                           ANG_W * (fabsf(p2 - b2) + fabsf(p3 - b3)) +
                           WID_W * smooth_l1(p4 - b4);
        }
    };
    auto advance = [&]() {
        finalize();
        ++tIdx;
        long long ip = predStart + (long long)tIdx * 64 + lane;
        c = (ip < n) ? counts[ip * stride] : 0;
        int incl = c;
#pragma unroll
        for (int d = 1; d < 64; d <<= 1) {
            int v = __shfl_up(incl, d, 64);
            if (lane >= d) incl += v;
        }
        int tot = __shfl(incl, 63, 64);
        int tBase = tEnd;
        cur = tBase + incl - c;
        segHi = cur + c;
        tEnd = tBase + tot;
        if (ip < n) {
            const float2* pp = (const float2*)(pred + ip * 6);
            float2 a = pp[0], b = pp[1], ww = pp[2];
            p0 = a.x; p1 = a.y; p2 = b.x; p3 = b.y; p4 = ww.x;
        }
        best = INFINITY;
        b0 = 0; b1 = 0; b2 = 0; b3 = 0; b4 = 0;
    };

    if (totalW > 0) {
        float2 r[12];
        float2(*mybuf)[CH * 3] = ring[wv];
        // prologue: issue chunk 0 (12 coalesced float2 per lane, clamped)
#pragma unroll
        for (int j = 0; j < 12; ++j)
            r[j] = win[min(lane + 64 * j, totalF2 - 1)];

        int nch = (totalW + CH - 1) / CH;
        for (int ck = 0; ck < nch; ++ck) {
            float2* bb = mybuf[ck & 1];
#pragma unroll
            for (int j = 0; j < 12; ++j) bb[lane + 64 * j] = r[j];
            if (ck + 1 < nch) {
                int kb = (ck + 1) * (CH * 3) + lane;
#pragma unroll
                for (int j = 0; j < 12; ++j)
                    r[j] = win[min(kb + 64 * j, totalF2 - 1)];
            }
            asm volatile("s_waitcnt lgkmcnt(0)" ::: "memory");
            __builtin_amdgcn_wave_barrier();

            int r0 = ck * CH;
            int cEnd = min(r0 + CH, totalW);
            while (tIdx < NT - 1 && tEnd <= r0) advance();
            for (;;) {
                int hiRow = min(cEnd, tEnd);
                int lo = max(cur, r0), hi = min(segHi, hiRow);
                for (int rr = lo; rr < hi; ++rr) {
                    int l3 = (rr - r0) * 3;
                    float2 ga = bb[l3], gb = bb[l3 + 1], gw = bb[l3 + 2];
                    float d0 = p0 - ga.x, d1 = p1 - ga.y;
                    float d2 = p2 - gb.x, d3 = p3 - gb.y;
                    float d4 = p4 - gw.x;
                    float dist = POS_W * (d0 * d0 + d1 * d1) +
                                 ANG_W * (d2 * d2 + d3 * d3) + WID_W * d4 * d4;
                    if (dist < best) {  // strict <: first occurrence
                        best = dist;
                        b0 = ga.x; b1 = ga.y; b2 = gb.x; b3 = gb.y; b4 = gw.x;
                    }
                }
                if (hi > cur) cur = hi;
                if (tEnd <= cEnd && tIdx < NT - 1) advance();
                else break;
            }
            __builtin_amdgcn_wave_barrier();
        }
    }
    // epilogue: finalize remaining tiles (incl. all-empty-window case)
    while (tIdx < NT - 1) advance();
    finalize();

    for (int o = 32; o > 0; o >>= 1) lossAcc += __shfl_down(lossAcc, o, 64);
    if (lane == 0) partials[w] = lossAcc;
}

// ---------------------------------------------------------------------------
// Kernel D: single-block reduction of per-wave partials -> out[0]
// ---------------------------------------------------------------------------
__global__ void k_reduce(const float* __restrict__ partials, int np,
                         float invN, float* __restrict__ out) {
    int t = threadIdx.x;
    float s = 0.0f;
    for (int j = t; j < np; j += 256) s += partials[j];
    for (int o = 32; o > 0; o >>= 1) s += __shfl_down(s, o, 64);
    __shared__ float fs[4];
    int lane = t & 63, wave = t >> 6;
    if (lane == 0) fs[wave] = s;
    __syncthreads();
    if (t == 0) out[0] = (fs[0] + fs[1] + fs[2] + fs[3]) * invN;
}

// ---------------------------------------------------------------------------
extern "C" void kernel_launch(void* const* d_in, const int* in_sizes, int n_in,
                              void* d_out, int out_size, void* d_ws,
                              size_t ws_size, hipStream_t stream) {
    const float* pred = (const float*)d_in[0];
    const float* tgt = (const float*)d_in[1];
    const int* counts = (const int*)d_in[2];
    int n = in_sizes[0] / 6;
    int stride = (in_sizes[2] == n) ? 1 : 2;  // int64 counts -> read low words
    int nw = (n + PW - 1) / PW;               // persistent waves
    int nbC = (nw + 3) / 4;                   // 4 waves per block

    int* spanSums = (int*)d_ws;
    int* waveBase = spanSums + nw;            // nw+1 entries
    float* partials = (float*)(waveBase + nw + 1);
    float* out = (float*)d_out;

    k_span_sums<<<nw, 256, 0, stream>>>(counts, stride, n, spanSums);
    k_scan_spans<<<1, 256, 0, stream>>>(spanSums, nw, waveBase);
    k_loss<<<nbC, 256, 0, stream>>>(pred, tgt, counts, stride, (long long)n,
                                    waveBase, nw, partials);
    k_reduce<<<1, 256, 0, stream>>>(partials, nw, 1.0f / n, out);
}